// Round 6
// baseline (184.102 us; speedup 1.0000x reference)
//
#include <hip/hip_runtime.h>

#define B_  2
#define S_  2048
#define E_  1024
#define H_  16
#define D_  64
#define NGLOB 2
#define NRAND 3
#define WIN 3

typedef __bf16 bf16x8 __attribute__((ext_vector_type(8)));
typedef float  f32x4  __attribute__((ext_vector_type(4)));

__device__ __forceinline__ unsigned short f2bf(float f) {
    unsigned u = __builtin_bit_cast(unsigned, f);
    unsigned r = u + 0x7FFFu + ((u >> 16) & 1u);   // RNE
    return (unsigned short)(r >> 16);
}
__device__ __forceinline__ float bf2f(unsigned short u) {
    return __builtin_bit_cast(float, (unsigned)u << 16);
}

// async global->LDS 16B DMA. LDS dest is wave-uniform base + lane*16.
__device__ __forceinline__ void g2l16(const unsigned short* g, unsigned short* l) {
    __builtin_amdgcn_global_load_lds(
        (const __attribute__((address_space(1))) unsigned*)g,
        (__attribute__((address_space(3))) unsigned*)l, 16, 0, 0);
}

// ---------------- fused fp32 -> bf16 conversion for x + 4 weights ----------------
__global__ __launch_bounds__(256)
void convert_all(const float* __restrict__ x,  const float* __restrict__ qw,
                 const float* __restrict__ kw, const float* __restrict__ vw,
                 const float* __restrict__ ow,
                 unsigned short* __restrict__ xb, unsigned short* __restrict__ wqkv,
                 unsigned short* __restrict__ wo) {
    const int XN = (B_ * S_ * E_) / 4;      // 1048576
    const int WN = (E_ * E_) / 4;           // 262144
    int i = blockIdx.x * blockDim.x + threadIdx.x;
    int r, loc;
    if (i < XN) { r = 0; loc = i; }
    else        { int j = i - XN; r = 1 + (j >> 18); loc = j & (WN - 1); }
    const float* src = r == 0 ? x : r == 1 ? qw : r == 2 ? kw : r == 3 ? vw : ow;
    float4 f = ((const float4*)src)[loc];
    ushort4 u;
    u.x = f2bf(f.x); u.y = f2bf(f.y); u.z = f2bf(f.z); u.w = f2bf(f.w);
    ushort4* dst = r == 0 ? (ushort4*)xb : r == 4 ? (ushort4*)wo
                 : (ushort4*)wqkv + (size_t)(r - 1) * WN;
    dst[loc] = u;
}

// ---------------- QKV GEMM: BK=64, XOR-swizzled LDS, 128x128, XCD-swizzled --------
__global__ __launch_bounds__(256, 3)
void gemm_qkv(const unsigned short* __restrict__ A,  // [M][K] bf16
              const unsigned short* __restrict__ W,  // [N][K] bf16
              const float* __restrict__ b0, const float* __restrict__ b1,
              const float* __restrict__ b2,
              unsigned short* __restrict__ Cb, int M, int N, int K) {
    __shared__ unsigned short sA[128 * 64];   // 16 KB
    __shared__ unsigned short sB[128 * 64];   // 16 KB
    const int nwg = gridDim.x;                // 768
    const int id  = (blockIdx.x & 7) * (nwg >> 3) + (blockIdx.x >> 3);
    const int bm = (id & 31) * 128;           // M/128 = 32
    const int bn = (id >> 5) * 128;
    const int t = threadIdx.x;
    const int lane = t & 63;
    const int wave = t >> 6;
    const int wm = wave >> 1, wn = wave & 1;
    const int lq = lane >> 4;
    const int lr = lane & 15;

    f32x4 acc[4][4] = {};

    for (int k0 = 0; k0 < K; k0 += 64) {
        const unsigned short* Abase = A + (size_t)bm * K + k0;
        const unsigned short* Wbase = W + (size_t)bn * K + k0;
        #pragma unroll
        for (int j = 0; j < 4; ++j) {             // 1024 chunks each
            int c = j * 256 + t;
            int row = c >> 3, cc = c & 7;
            int gcol = ((cc ^ (row & 7)) << 3);   // swizzled source col
            int dst = j * 2048 + wave * 512;      // wave-uniform elem offset
            g2l16(Abase + (size_t)row * K + gcol, sA + dst);
            g2l16(Wbase + (size_t)row * K + gcol, sB + dst);
        }
        __syncthreads();

        #pragma unroll
        for (int ks = 0; ks < 2; ++ks) {
            const int sw = (((ks << 2) + lq) ^ (lr & 7)) << 3;
            bf16x8 af[4], bfr[4];
            #pragma unroll
            for (int i = 0; i < 4; ++i)
                af[i] = *(const bf16x8*)&sA[(wm * 64 + i * 16 + lr) * 64 + sw];
            #pragma unroll
            for (int j = 0; j < 4; ++j)
                bfr[j] = *(const bf16x8*)&sB[(wn * 64 + j * 16 + lr) * 64 + sw];
            #pragma unroll
            for (int i = 0; i < 4; ++i)
                #pragma unroll
                for (int j = 0; j < 4; ++j)
                    acc[i][j] = __builtin_amdgcn_mfma_f32_16x16x32_bf16(af[i], bfr[j], acc[i][j], 0, 0, 0);
        }
        __syncthreads();
    }

    #pragma unroll
    for (int i = 0; i < 4; ++i) {
        int row0 = bm + wm * 64 + i * 16 + lq * 4;
        #pragma unroll
        for (int j = 0; j < 4; ++j) {
            int col = bn + wn * 64 + j * 16 + lr;
            const float* bp = col < E_ ? b0 : (col < 2 * E_ ? b1 : b2);
            float bv = bp[col & (E_ - 1)];
            #pragma unroll
            for (int r = 0; r < 4; ++r)
                Cb[(size_t)(row0 + r) * N + col] = f2bf(acc[i][j][r] + bv);
        }
    }
}

// ---------------- O GEMM: 128x128 tile, fp32 out, XCD-swizzled ----------------
__global__ __launch_bounds__(256, 3)
void gemm_o(const unsigned short* __restrict__ A,   // [M][K] bf16 (attn)
            const unsigned short* __restrict__ W,   // [N][K] bf16 (wo)
            const float* __restrict__ bias,
            float* __restrict__ Cf, int M, int N, int K) {
    __shared__ unsigned short sA[128 * 64];   // 16 KB
    __shared__ unsigned short sB[128 * 64];   // 16 KB
    const int nwg = gridDim.x;                // 256
    const int id  = (blockIdx.x & 7) * (nwg >> 3) + (blockIdx.x >> 3);
    const int bm = (id & 31) * 128;           // M/128 = 32
    const int bn = (id >> 5) * 128;
    const int t = threadIdx.x;
    const int lane = t & 63;
    const int wave = t >> 6;
    const int wm = wave >> 1, wn = wave & 1;
    const int lq = lane >> 4;
    const int lr = lane & 15;

    f32x4 acc[4][4] = {};

    for (int k0 = 0; k0 < K; k0 += 64) {
        const unsigned short* Abase = A + (size_t)bm * K + k0;
        const unsigned short* Wbase = W + (size_t)bn * K + k0;
        #pragma unroll
        for (int j = 0; j < 4; ++j) {
            int c = j * 256 + t;
            int row = c >> 3, cc = c & 7;
            int gcol = ((cc ^ (row & 7)) << 3);
            int dst = j * 2048 + wave * 512;
            g2l16(Abase + (size_t)row * K + gcol, sA + dst);
            g2l16(Wbase + (size_t)row * K + gcol, sB + dst);
        }
        __syncthreads();

        #pragma unroll
        for (int ks = 0; ks < 2; ++ks) {
            const int sw = (((ks << 2) + lq) ^ (lr & 7)) << 3;
            bf16x8 af[4], bfr[4];
            #pragma unroll
            for (int i = 0; i < 4; ++i)
                af[i] = *(const bf16x8*)&sA[(wm * 64 + i * 16 + lr) * 64 + sw];
            #pragma unroll
            for (int j = 0; j < 4; ++j)
                bfr[j] = *(const bf16x8*)&sB[(wn * 64 + j * 16 + lr) * 64 + sw];
            #pragma unroll
            for (int i = 0; i < 4; ++i)
                #pragma unroll
                for (int j = 0; j < 4; ++j)
                    acc[i][j] = __builtin_amdgcn_mfma_f32_16x16x32_bf16(af[i], bfr[j], acc[i][j], 0, 0, 0);
        }
        __syncthreads();
    }

    #pragma unroll
    for (int i = 0; i < 4; ++i) {
        int row0 = bm + wm * 64 + i * 16 + lq * 4;
        #pragma unroll
        for (int j = 0; j < 4; ++j) {
            int col = bn + wn * 64 + j * 16 + lr;
            float bv = bias[col];
            #pragma unroll
            for (int r = 0; r < 4; ++r)
                Cf[(size_t)(row0 + r) * N + col] = acc[i][j][r] + bv;
        }
    }
}

// ---------------- fused: row-streaming global path + sparse rows -----------------
// R6: blocks [0,256) = (b, 16-row chunk). Each block reads the FULL K and V slices
// of 16 consecutive rows (64 lanes x 32B = whole 2KB head-row per load instr,
// 16 independent loads/wave up front -> contiguous streaming, ~512 lines in
// flight/wave) and computes scores+PV for ALL 16 heads and BOTH global queries in
// one pass. lane=(head, dim-quarter). Wave-level 4-key flash partials -> LDS
// combine -> per-chunk (m, sum, unnormalized O) to scratch; gattn_fin merges 128
// chunks/tuple. Replaces the per-head 128B-gather pattern that crawled at ~1TB/s.
// Blocks [256,1280) = sparse rows, one wave per row (unchanged).
__global__ __launch_bounds__(256)
void attn_fused(const unsigned short* __restrict__ qkv,
                const int* __restrict__ rnd,
                float* __restrict__ gaccp, float* __restrict__ gms,
                unsigned short* __restrict__ attn) {
    const int NB = B_ * (S_ - 2);     // 4092
    int t = threadIdx.x;

    if (blockIdx.x < 256) {
        // ---- one (b, 16-key chunk) per block; all heads, both global queries ----
        int g = blockIdx.x;
        int b = g >> 7, ck = g & 127;
        int w = t >> 6, l = t & 63;
        int h = l >> 2, dseg = l & 3;          // head, dim-quarter (16 dims)
        int key0 = ck * 16 + w * 4;            // this wave's 4 keys

        __shared__ float sm[4][16][4];         // [wave][head][m0,sum0,m1,sum1]
        __shared__ float ovv[4][2][16][68];    // [wave][i][head][dim(+pad)] ~34.8KB

        // Q for both global rows, this lane's 16 dims
        const unsigned short* qb0 = qkv + (size_t)(b * S_) * 3072 + h * 64 + dseg * 16;
        const unsigned short* qb1 = qb0 + 3072;
        bf16x8 q0a = *(const bf16x8*)qb0, q0b = *(const bf16x8*)(qb0 + 8);
        bf16x8 q1a = *(const bf16x8*)qb1, q1b = *(const bf16x8*)(qb1 + 8);

        // K,V for 4 keys: 16 independent 2KB-span loads, issued up front
        bf16x8 ka[4], kb[4], va[4], vb[4];
        #pragma unroll
        for (int j = 0; j < 4; ++j) {
            const unsigned short* kr =
                qkv + (size_t)(b * S_ + key0 + j) * 3072 + E_ + h * 64 + dseg * 16;
            ka[j] = *(const bf16x8*)kr;  kb[j] = *(const bf16x8*)(kr + 8);
            const unsigned short* vr = kr + E_;
            va[j] = *(const bf16x8*)vr;  vb[j] = *(const bf16x8*)(vr + 8);
        }

        // scores for both queries, 4 keys
        float s0[4], s1[4];
        #pragma unroll
        for (int j = 0; j < 4; ++j) {
            float a0 = 0.f, a1 = 0.f;
            #pragma unroll
            for (int e = 0; e < 8; ++e) {
                float k1 = (float)ka[j][e], k2 = (float)kb[j][e];
                a0 += (float)q0a[e] * k1 + (float)q0b[e] * k2;
                a1 += (float)q1a[e] * k1 + (float)q1b[e] * k2;
            }
            a0 += __shfl_xor(a0, 1); a0 += __shfl_xor(a0, 2);
            a1 += __shfl_xor(a1, 1); a1 += __shfl_xor(a1, 2);
            s0[j] = a0 * 0.125f; s1[j] = a1 * 0.125f;
        }

        // wave-local flash partials over 4 keys
        float m0 = fmaxf(fmaxf(s0[0], s0[1]), fmaxf(s0[2], s0[3]));
        float m1 = fmaxf(fmaxf(s1[0], s1[1]), fmaxf(s1[2], s1[3]));
        float e0[4], e1[4], sum0 = 0.f, sum1 = 0.f;
        #pragma unroll
        for (int j = 0; j < 4; ++j) {
            e0[j] = __expf(s0[j] - m0); sum0 += e0[j];
            e1[j] = __expf(s1[j] - m1); sum1 += e1[j];
        }
        float o0[16] = {}, o1[16] = {};
        #pragma unroll
        for (int j = 0; j < 4; ++j)
            #pragma unroll
            for (int e = 0; e < 8; ++e) {
                float v1 = (float)va[j][e], v2 = (float)vb[j][e];
                o0[e] += e0[j] * v1;  o0[8 + e] += e0[j] * v2;
                o1[e] += e1[j] * v1;  o1[8 + e] += e1[j] * v2;
            }

        if (dseg == 0) {
            sm[w][h][0] = m0; sm[w][h][1] = sum0;
            sm[w][h][2] = m1; sm[w][h][3] = sum1;
        }
        #pragma unroll
        for (int e = 0; e < 16; ++e) {
            ovv[w][0][h][dseg * 16 + e] = o0[e];
            ovv[w][1][h][dseg * 16 + e] = o1[e];
        }
        __syncthreads();

        // combine 4 waves -> per-chunk partial; thread handles 8 of 2048 outputs
        #pragma unroll
        for (int r = 0; r < 8; ++r) {
            int ot = r * 256 + t;                       // i*1024 + h*64 + d
            int ii = ot >> 10, hh = (ot >> 6) & 15, d = ot & 63;
            float M = -1e30f;
            #pragma unroll
            for (int ww = 0; ww < 4; ++ww) M = fmaxf(M, sm[ww][hh][ii * 2]);
            float den = 0.f, num = 0.f;
            #pragma unroll
            for (int ww = 0; ww < 4; ++ww) {
                float f = __expf(sm[ww][hh][ii * 2] - M);
                den += sm[ww][hh][ii * 2 + 1] * f;
                num += ovv[ww][ii][hh][d] * f;
            }
            int tup = b * 32 + ii * 16 + hh;
            gaccp[((size_t)tup * 128 + ck) * D_ + d] = num;
            if (d == 0) {
                gms[((size_t)tup * 128 + ck) * 2]     = M;
                gms[((size_t)tup * 128 + ck) * 2 + 1] = den;
            }
        }
        return;
    }

    // ---- sparse rows: one wave per row ----
    int bb = blockIdx.x - 256;                        // [0,1024)
    int bidx = (bb & 7) * 128 + (bb >> 3);            // XCD swizzle
    int w = t >> 6, l = t & 63;
    int row = bidx * 4 + w;
    bool valid = row < NB;
    int b = row / (S_ - 2);
    int i = row % (S_ - 2) + 2;
    if (!valid) { b = 0; i = 2; }

    __shared__ int   cols_s[4][12];
    __shared__ int   ncol_sh[4];
    __shared__ float pr_s[4][16 * 13 + 3];

    const bf16x8* qp = (const bf16x8*)(qkv + (size_t)(b * S_ + i) * 3072);
    bf16x8 q0 = qp[l * 2], q1 = qp[l * 2 + 1];
    float qreg[16];
    #pragma unroll
    for (int j = 0; j < 8; ++j) { qreg[j] = (float)q0[j]; qreg[8 + j] = (float)q1[j]; }

    if (l == 0) {
        int* cols = cols_s[w];
        int n = 0;
        cols[n++] = 0; cols[n++] = 1;
        int lo = i - WIN; if (lo < NGLOB) lo = NGLOB;
        int hi = i + WIN; if (hi > S_ - 1) hi = S_ - 1;
        for (int j = lo; j <= hi; ++j) cols[n++] = j;
        for (int r = 0; r < NRAND; ++r) {
            int c = rnd[i * NRAND + r];
            bool dup = false;
            for (int q = 0; q < n; ++q) dup = dup || (cols[q] == c);
            if (!dup) cols[n++] = c;
        }
        ncol_sh[w] = n;
        for (int q = n; q < 12; ++q) cols[q] = 0;
    }
    __syncthreads();
    const int n = ncol_sh[w];
    const int h4 = l >> 2;

    float sco[12];
    #pragma unroll
    for (int c = 0; c < 12; ++c) {
        const bf16x8* kp = (const bf16x8*)(qkv + (size_t)(b * S_ + cols_s[w][c]) * 3072 + E_);
        bf16x8 k0 = kp[l * 2], k1 = kp[l * 2 + 1];
        float s = 0.f;
        #pragma unroll
        for (int j = 0; j < 8; ++j) s += qreg[j] * (float)k0[j] + qreg[8 + j] * (float)k1[j];
        s += __shfl_xor(s, 1);
        s += __shfl_xor(s, 2);
        sco[c] = (c < n) ? s * 0.125f : -1e30f;
    }

    if ((l & 3) == 0) {
        float m = -1e30f;
        #pragma unroll
        for (int c = 0; c < 12; ++c) m = fmaxf(m, sco[c]);
        float sum = 0.f;
        #pragma unroll
        for (int c = 0; c < 12; ++c) { float e = __expf(sco[c] - m); sco[c] = e; sum += e; }
        float inv = 1.f / sum;
        #pragma unroll
        for (int c = 0; c < 12; ++c) pr_s[w][h4 * 13 + c] = sco[c] * inv;
    }
    __syncthreads();

    float o[16] = {};
    #pragma unroll
    for (int c = 0; c < 12; ++c) {
        float p = pr_s[w][h4 * 13 + c];
        const bf16x8* vp = (const bf16x8*)(qkv + (size_t)(b * S_ + cols_s[w][c]) * 3072 + 2 * E_);
        bf16x8 v0 = vp[l * 2], v1 = vp[l * 2 + 1];
        #pragma unroll
        for (int j = 0; j < 8; ++j) { o[j] += p * (float)v0[j]; o[8 + j] += p * (float)v1[j]; }
    }

    if (valid) {
        ushort4 u0, u1, u2, u3;
        u0.x = f2bf(o[0]);  u0.y = f2bf(o[1]);  u0.z = f2bf(o[2]);  u0.w = f2bf(o[3]);
        u1.x = f2bf(o[4]);  u1.y = f2bf(o[5]);  u1.z = f2bf(o[6]);  u1.w = f2bf(o[7]);
        u2.x = f2bf(o[8]);  u2.y = f2bf(o[9]);  u2.z = f2bf(o[10]); u2.w = f2bf(o[11]);
        u3.x = f2bf(o[12]); u3.y = f2bf(o[13]); u3.z = f2bf(o[14]); u3.w = f2bf(o[15]);
        ushort4* op = (ushort4*)(attn + (size_t)(b * S_ + i) * E_ + l * 16);
        op[0] = u0; op[1] = u1; op[2] = u2; op[3] = u3;
    }
}

// merge 128 chunk partials per tuple
__global__ __launch_bounds__(256)
void gattn_fin(const float* __restrict__ gaccp, const float* __restrict__ gms,
               unsigned short* __restrict__ attn) {
    int gid = blockIdx.x * 256 + threadIdx.x;   // 4096
    int tup = gid >> 6, d = gid & 63;
    int b = tup >> 5, i = (tup >> 4) & 1, h = tup & 15;
    float M = -1e30f;
    #pragma unroll 8
    for (int c = 0; c < 128; ++c) M = fmaxf(M, gms[((size_t)tup * 128 + c) * 2]);
    float den = 0.f, num = 0.f;
    #pragma unroll 8
    for (int c = 0; c < 128; ++c) {
        float f = __expf(gms[((size_t)tup * 128 + c) * 2] - M);
        den += gms[((size_t)tup * 128 + c) * 2 + 1] * f;
        num += gaccp[((size_t)tup * 128 + c) * D_ + d] * f;
    }
    attn[(size_t)(b * S_ + i) * E_ + h * D_ + d] = f2bf(num / den);
}

extern "C" void kernel_launch(void* const* d_in, const int* in_sizes, int n_in,
                              void* d_out, int out_size, void* d_ws, size_t ws_size,
                              hipStream_t stream) {
    const float* x   = (const float*)d_in[0];
    const int*   rnd = (const int*)d_in[1];
    const float* qw  = (const float*)d_in[2];
    const float* qb  = (const float*)d_in[3];
    const float* kw  = (const float*)d_in[4];
    const float* kb  = (const float*)d_in[5];
    const float* vw  = (const float*)d_in[6];
    const float* vb  = (const float*)d_in[7];
    const float* ow  = (const float*)d_in[8];
    const float* ob  = (const float*)d_in[9];
    float* out = (float*)d_out;

    char* ws = (char*)d_ws;
    unsigned short* xb    = (unsigned short*)(ws);                       // 8 MB (dead after QKV GEMM)
    unsigned short* wqkv  = (unsigned short*)(ws + 8388608);             // 6 MB
    unsigned short* wo    = (unsigned short*)(ws + 14680064);            // 2 MB
    unsigned short* qkv   = (unsigned short*)(ws + 16777216);            // 24 MB
    unsigned short* attn  = (unsigned short*)(ws + 41943040);            // 8 MB
    float*          gaccp = (float*)(ws);                                // 2 MB (overlaps dead xb)
    float*          gms   = (float*)(ws + 2097152);                      // 64 KB

    const int M = B_ * S_;   // 4096

    {
        int total4 = (M * E_ + 4 * E_ * E_) / 4;
        convert_all<<<total4 / 256, 256, 0, stream>>>(x, qw, kw, vw, ow, xb, wqkv, wo);
    }

    // QKV GEMM: [4096][3072] bf16, BK=64 swizzled, XCD-swizzled 1D grid
    gemm_qkv<<<768, 256, 0, stream>>>(xb, wqkv, qb, kb, vb, qkv, M, 3 * E_, E_);

    // row-streaming global chunks (256) + sparse rows (1024), one dispatch
    attn_fused<<<256 + 1024, 256, 0, stream>>>(qkv, rnd, gaccp, gms, attn);

    // merge global-row partials (128 chunks/tuple)
    gattn_fin<<<16, 256, 0, stream>>>(gaccp, gms, attn);

    // O GEMM -> fp32 out, 128x128 tile, XCD-swizzled 1D grid
    gemm_o<<<256, 256, 0, stream>>>(attn, wo, ob, out, M, E_, E_);
}

// Round 7
// 169.554 us; speedup vs baseline: 1.0858x; 1.0858x over previous
//
#include <hip/hip_runtime.h>

#define B_  2
#define S_  2048
#define E_  1024
#define H_  16
#define D_  64
#define NGLOB 2
#define NRAND 3
#define WIN 3

typedef __bf16 bf16x8 __attribute__((ext_vector_type(8)));
typedef float  f32x4  __attribute__((ext_vector_type(4)));

__device__ __forceinline__ unsigned short f2bf(float f) {
    unsigned u = __builtin_bit_cast(unsigned, f);
    unsigned r = u + 0x7FFFu + ((u >> 16) & 1u);   // RNE
    return (unsigned short)(r >> 16);
}
__device__ __forceinline__ float bf2f(unsigned short u) {
    return __builtin_bit_cast(float, (unsigned)u << 16);
}

// async global->LDS 16B DMA. LDS dest is wave-uniform base + lane*16.
__device__ __forceinline__ void g2l16(const unsigned short* g, unsigned short* l) {
    __builtin_amdgcn_global_load_lds(
        (const __attribute__((address_space(1))) unsigned*)g,
        (__attribute__((address_space(3))) unsigned*)l, 16, 0, 0);
}

// ---------------- fused fp32 -> bf16 conversion for x + 4 weights ----------------
__global__ __launch_bounds__(256)
void convert_all(const float* __restrict__ x,  const float* __restrict__ qw,
                 const float* __restrict__ kw, const float* __restrict__ vw,
                 const float* __restrict__ ow,
                 unsigned short* __restrict__ xb, unsigned short* __restrict__ wqkv,
                 unsigned short* __restrict__ wo) {
    const int XN = (B_ * S_ * E_) / 4;      // 1048576
    const int WN = (E_ * E_) / 4;           // 262144
    int i = blockIdx.x * blockDim.x + threadIdx.x;
    int r, loc;
    if (i < XN) { r = 0; loc = i; }
    else        { int j = i - XN; r = 1 + (j >> 18); loc = j & (WN - 1); }
    const float* src = r == 0 ? x : r == 1 ? qw : r == 2 ? kw : r == 3 ? vw : ow;
    float4 f = ((const float4*)src)[loc];
    ushort4 u;
    u.x = f2bf(f.x); u.y = f2bf(f.y); u.z = f2bf(f.z); u.w = f2bf(f.w);
    ushort4* dst = r == 0 ? (ushort4*)xb : r == 4 ? (ushort4*)wo
                 : (ushort4*)wqkv + (size_t)(r - 1) * WN;
    dst[loc] = u;
}

// ---------------- QKV GEMM: BK=64, XOR-swizzled LDS, 128x128, XCD-swizzled --------
__global__ __launch_bounds__(256, 3)
void gemm_qkv(const unsigned short* __restrict__ A,  // [M][K] bf16
              const unsigned short* __restrict__ W,  // [N][K] bf16
              const float* __restrict__ b0, const float* __restrict__ b1,
              const float* __restrict__ b2,
              unsigned short* __restrict__ Cb, int M, int N, int K) {
    __shared__ unsigned short sA[128 * 64];   // 16 KB
    __shared__ unsigned short sB[128 * 64];   // 16 KB
    const int nwg = gridDim.x;                // 768
    const int id  = (blockIdx.x & 7) * (nwg >> 3) + (blockIdx.x >> 3);
    const int bm = (id & 31) * 128;           // M/128 = 32
    const int bn = (id >> 5) * 128;
    const int t = threadIdx.x;
    const int lane = t & 63;
    const int wave = t >> 6;
    const int wm = wave >> 1, wn = wave & 1;
    const int lq = lane >> 4;
    const int lr = lane & 15;

    f32x4 acc[4][4] = {};

    for (int k0 = 0; k0 < K; k0 += 64) {
        const unsigned short* Abase = A + (size_t)bm * K + k0;
        const unsigned short* Wbase = W + (size_t)bn * K + k0;
        #pragma unroll
        for (int j = 0; j < 4; ++j) {             // 1024 chunks each
            int c = j * 256 + t;
            int row = c >> 3, cc = c & 7;
            int gcol = ((cc ^ (row & 7)) << 3);   // swizzled source col
            int dst = j * 2048 + wave * 512;      // wave-uniform elem offset
            g2l16(Abase + (size_t)row * K + gcol, sA + dst);
            g2l16(Wbase + (size_t)row * K + gcol, sB + dst);
        }
        __syncthreads();

        #pragma unroll
        for (int ks = 0; ks < 2; ++ks) {
            const int sw = (((ks << 2) + lq) ^ (lr & 7)) << 3;
            bf16x8 af[4], bfr[4];
            #pragma unroll
            for (int i = 0; i < 4; ++i)
                af[i] = *(const bf16x8*)&sA[(wm * 64 + i * 16 + lr) * 64 + sw];
            #pragma unroll
            for (int j = 0; j < 4; ++j)
                bfr[j] = *(const bf16x8*)&sB[(wn * 64 + j * 16 + lr) * 64 + sw];
            #pragma unroll
            for (int i = 0; i < 4; ++i)
                #pragma unroll
                for (int j = 0; j < 4; ++j)
                    acc[i][j] = __builtin_amdgcn_mfma_f32_16x16x32_bf16(af[i], bfr[j], acc[i][j], 0, 0, 0);
        }
        __syncthreads();
    }

    #pragma unroll
    for (int i = 0; i < 4; ++i) {
        int row0 = bm + wm * 64 + i * 16 + lq * 4;
        #pragma unroll
        for (int j = 0; j < 4; ++j) {
            int col = bn + wn * 64 + j * 16 + lr;
            const float* bp = col < E_ ? b0 : (col < 2 * E_ ? b1 : b2);
            float bv = bp[col & (E_ - 1)];
            #pragma unroll
            for (int r = 0; r < 4; ++r)
                Cb[(size_t)(row0 + r) * N + col] = f2bf(acc[i][j][r] + bv);
        }
    }
}

// ---------------- O GEMM: 128x128 tile, fp32 out, XCD-swizzled ----------------
__global__ __launch_bounds__(256, 3)
void gemm_o(const unsigned short* __restrict__ A,   // [M][K] bf16 (attn)
            const unsigned short* __restrict__ W,   // [N][K] bf16 (wo)
            const float* __restrict__ bias,
            float* __restrict__ Cf, int M, int N, int K) {
    __shared__ unsigned short sA[128 * 64];   // 16 KB
    __shared__ unsigned short sB[128 * 64];   // 16 KB
    const int nwg = gridDim.x;                // 256
    const int id  = (blockIdx.x & 7) * (nwg >> 3) + (blockIdx.x >> 3);
    const int bm = (id & 31) * 128;           // M/128 = 32
    const int bn = (id >> 5) * 128;
    const int t = threadIdx.x;
    const int lane = t & 63;
    const int wave = t >> 6;
    const int wm = wave >> 1, wn = wave & 1;
    const int lq = lane >> 4;
    const int lr = lane & 15;

    f32x4 acc[4][4] = {};

    for (int k0 = 0; k0 < K; k0 += 64) {
        const unsigned short* Abase = A + (size_t)bm * K + k0;
        const unsigned short* Wbase = W + (size_t)bn * K + k0;
        #pragma unroll
        for (int j = 0; j < 4; ++j) {
            int c = j * 256 + t;
            int row = c >> 3, cc = c & 7;
            int gcol = ((cc ^ (row & 7)) << 3);
            int dst = j * 2048 + wave * 512;
            g2l16(Abase + (size_t)row * K + gcol, sA + dst);
            g2l16(Wbase + (size_t)row * K + gcol, sB + dst);
        }
        __syncthreads();

        #pragma unroll
        for (int ks = 0; ks < 2; ++ks) {
            const int sw = (((ks << 2) + lq) ^ (lr & 7)) << 3;
            bf16x8 af[4], bfr[4];
            #pragma unroll
            for (int i = 0; i < 4; ++i)
                af[i] = *(const bf16x8*)&sA[(wm * 64 + i * 16 + lr) * 64 + sw];
            #pragma unroll
            for (int j = 0; j < 4; ++j)
                bfr[j] = *(const bf16x8*)&sB[(wn * 64 + j * 16 + lr) * 64 + sw];
            #pragma unroll
            for (int i = 0; i < 4; ++i)
                #pragma unroll
                for (int j = 0; j < 4; ++j)
                    acc[i][j] = __builtin_amdgcn_mfma_f32_16x16x32_bf16(af[i], bfr[j], acc[i][j], 0, 0, 0);
        }
        __syncthreads();
    }

    #pragma unroll
    for (int i = 0; i < 4; ++i) {
        int row0 = bm + wm * 64 + i * 16 + lq * 4;
        #pragma unroll
        for (int j = 0; j < 4; ++j) {
            int col = bn + wn * 64 + j * 16 + lr;
            float bv = bias[col];
            #pragma unroll
            for (int r = 0; r < 4; ++r)
                Cf[(size_t)(row0 + r) * N + col] = acc[i][j][r] + bv;
        }
    }
}

// ---------------- fused: row-streaming global path + sparse rows -----------------
// R7: R6 streaming global path, restructured for low VGPR (two-phase K/V staging:
// K[0..3]+V[0..1] up front, scores, softmax partials, PV 0-1 while V[2..3] load).
// __launch_bounds__(256,5) caps VGPR ~102 so the sparse path keeps 5 waves/SIMD
// (R6's 16-reg-vec staging pushed the shared budget to ~140 -> sparse occupancy
// collapse, the suspected R6 regression).
__global__ __launch_bounds__(256, 5)
void attn_fused(const unsigned short* __restrict__ qkv,
                const int* __restrict__ rnd,
                float* __restrict__ gaccp, float* __restrict__ gms,
                unsigned short* __restrict__ attn) {
    const int NB = B_ * (S_ - 2);     // 4092
    int t = threadIdx.x;

    if (blockIdx.x < 256) {
        // ---- one (b, 16-key chunk) per block; all heads, both global queries ----
        int g = blockIdx.x;
        int b = g >> 7, ck = g & 127;
        int w = t >> 6, l = t & 63;
        int h = l >> 2, dseg = l & 3;          // head, dim-quarter (16 dims/lane)
        int key0 = ck * 16 + w * 4;            // this wave's 4 keys

        __shared__ float sm[4][16][4];         // [wave][head][m0,sum0,m1,sum1]
        __shared__ float ovv[4][2][16][68];    // [wave][i][head][dim(+pad)] ~34.8KB

        // Q for both global rows, this lane's 16 dims
        const unsigned short* qb0 = qkv + (size_t)(b * S_) * 3072 + h * 64 + dseg * 16;
        const unsigned short* qb1 = qb0 + 3072;
        bf16x8 q0a = *(const bf16x8*)qb0, q0b = *(const bf16x8*)(qb0 + 8);
        bf16x8 q1a = *(const bf16x8*)qb1, q1b = *(const bf16x8*)(qb1 + 8);

        // phase 1: K for 4 keys (32 VGPR) + V for keys 0,1 (16 VGPR)
        const unsigned short* kr0 =
            qkv + (size_t)(b * S_ + key0) * 3072 + E_ + h * 64 + dseg * 16;
        bf16x8 ka[4], kb[4];
        #pragma unroll
        for (int j = 0; j < 4; ++j) {
            ka[j] = *(const bf16x8*)(kr0 + (size_t)j * 3072);
            kb[j] = *(const bf16x8*)(kr0 + (size_t)j * 3072 + 8);
        }
        bf16x8 va0 = *(const bf16x8*)(kr0 + E_);
        bf16x8 vb0 = *(const bf16x8*)(kr0 + E_ + 8);
        bf16x8 va1 = *(const bf16x8*)(kr0 + 3072 + E_);
        bf16x8 vb1 = *(const bf16x8*)(kr0 + 3072 + E_ + 8);

        // scores for both queries, 4 keys (4-lane dot + 2-level shfl)
        float s0[4], s1[4];
        #pragma unroll
        for (int j = 0; j < 4; ++j) {
            float a0 = 0.f, a1 = 0.f;
            #pragma unroll
            for (int e = 0; e < 8; ++e) {
                float k1 = (float)ka[j][e], k2 = (float)kb[j][e];
                a0 += (float)q0a[e] * k1 + (float)q0b[e] * k2;
                a1 += (float)q1a[e] * k1 + (float)q1b[e] * k2;
            }
            a0 += __shfl_xor(a0, 1); a0 += __shfl_xor(a0, 2);
            a1 += __shfl_xor(a1, 1); a1 += __shfl_xor(a1, 2);
            s0[j] = a0 * 0.125f; s1[j] = a1 * 0.125f;
        }

        // wave-local flash partials over 4 keys
        float m0 = fmaxf(fmaxf(s0[0], s0[1]), fmaxf(s0[2], s0[3]));
        float m1 = fmaxf(fmaxf(s1[0], s1[1]), fmaxf(s1[2], s1[3]));
        float e0[4], e1[4], sum0 = 0.f, sum1 = 0.f;
        #pragma unroll
        for (int j = 0; j < 4; ++j) {
            e0[j] = __expf(s0[j] - m0); sum0 += e0[j];
            e1[j] = __expf(s1[j] - m1); sum1 += e1[j];
        }

        // phase 2: PV keys 0,1; V keys 2,3 load in parallel
        bf16x8 va2 = *(const bf16x8*)(kr0 + 2 * 3072 + E_);
        bf16x8 vb2 = *(const bf16x8*)(kr0 + 2 * 3072 + E_ + 8);
        bf16x8 va3 = *(const bf16x8*)(kr0 + 3 * 3072 + E_);
        bf16x8 vb3 = *(const bf16x8*)(kr0 + 3 * 3072 + E_ + 8);

        float o0[16] = {}, o1[16] = {};
        #pragma unroll
        for (int e = 0; e < 8; ++e) {
            float v1 = (float)va0[e], v2 = (float)vb0[e];
            float v3 = (float)va1[e], v4 = (float)vb1[e];
            o0[e]     += e0[0] * v1 + e0[1] * v3;
            o0[8 + e] += e0[0] * v2 + e0[1] * v4;
            o1[e]     += e1[0] * v1 + e1[1] * v3;
            o1[8 + e] += e1[0] * v2 + e1[1] * v4;
        }
        #pragma unroll
        for (int e = 0; e < 8; ++e) {
            float v1 = (float)va2[e], v2 = (float)vb2[e];
            float v3 = (float)va3[e], v4 = (float)vb3[e];
            o0[e]     += e0[2] * v1 + e0[3] * v3;
            o0[8 + e] += e0[2] * v2 + e0[3] * v4;
            o1[e]     += e1[2] * v1 + e1[3] * v3;
            o1[8 + e] += e1[2] * v2 + e1[3] * v4;
        }

        if (dseg == 0) {
            sm[w][h][0] = m0; sm[w][h][1] = sum0;
            sm[w][h][2] = m1; sm[w][h][3] = sum1;
        }
        #pragma unroll
        for (int e = 0; e < 16; ++e) {
            ovv[w][0][h][dseg * 16 + e] = o0[e];
            ovv[w][1][h][dseg * 16 + e] = o1[e];
        }
        __syncthreads();

        // combine 4 waves -> per-chunk partial; thread handles 8 of 2048 outputs
        #pragma unroll
        for (int r = 0; r < 8; ++r) {
            int ot = r * 256 + t;                       // i*1024 + h*64 + d
            int ii = ot >> 10, hh = (ot >> 6) & 15, d = ot & 63;
            float M = -1e30f;
            #pragma unroll
            for (int ww = 0; ww < 4; ++ww) M = fmaxf(M, sm[ww][hh][ii * 2]);
            float den = 0.f, num = 0.f;
            #pragma unroll
            for (int ww = 0; ww < 4; ++ww) {
                float f = __expf(sm[ww][hh][ii * 2] - M);
                den += sm[ww][hh][ii * 2 + 1] * f;
                num += ovv[ww][ii][hh][d] * f;
            }
            int tup = b * 32 + ii * 16 + hh;
            gaccp[((size_t)tup * 128 + ck) * D_ + d] = num;
            if (d == 0) {
                gms[((size_t)tup * 128 + ck) * 2]     = M;
                gms[((size_t)tup * 128 + ck) * 2 + 1] = den;
            }
        }
        return;
    }

    // ---- sparse rows: one wave per row ----
    int bb = blockIdx.x - 256;                        // [0,1024)
    int bidx = (bb & 7) * 128 + (bb >> 3);            // XCD swizzle
    int w = t >> 6, l = t & 63;
    int row = bidx * 4 + w;
    bool valid = row < NB;
    int b = row / (S_ - 2);
    int i = row % (S_ - 2) + 2;
    if (!valid) { b = 0; i = 2; }

    __shared__ int   cols_s[4][12];
    __shared__ int   ncol_sh[4];
    __shared__ float pr_s[4][16 * 13 + 3];

    const bf16x8* qp = (const bf16x8*)(qkv + (size_t)(b * S_ + i) * 3072);
    bf16x8 q0 = qp[l * 2], q1 = qp[l * 2 + 1];
    float qreg[16];
    #pragma unroll
    for (int j = 0; j < 8; ++j) { qreg[j] = (float)q0[j]; qreg[8 + j] = (float)q1[j]; }

    if (l == 0) {
        int* cols = cols_s[w];
        int n = 0;
        cols[n++] = 0; cols[n++] = 1;
        int lo = i - WIN; if (lo < NGLOB) lo = NGLOB;
        int hi = i + WIN; if (hi > S_ - 1) hi = S_ - 1;
        for (int j = lo; j <= hi; ++j) cols[n++] = j;
        for (int r = 0; r < NRAND; ++r) {
            int c = rnd[i * NRAND + r];
            bool dup = false;
            for (int q = 0; q < n; ++q) dup = dup || (cols[q] == c);
            if (!dup) cols[n++] = c;
        }
        ncol_sh[w] = n;
        for (int q = n; q < 12; ++q) cols[q] = 0;
    }
    __syncthreads();
    const int n = ncol_sh[w];
    const int h4 = l >> 2;

    float sco[12];
    #pragma unroll
    for (int c = 0; c < 12; ++c) {
        const bf16x8* kp = (const bf16x8*)(qkv + (size_t)(b * S_ + cols_s[w][c]) * 3072 + E_);
        bf16x8 k0 = kp[l * 2], k1 = kp[l * 2 + 1];
        float s = 0.f;
        #pragma unroll
        for (int j = 0; j < 8; ++j) s += qreg[j] * (float)k0[j] + qreg[8 + j] * (float)k1[j];
        s += __shfl_xor(s, 1);
        s += __shfl_xor(s, 2);
        sco[c] = (c < n) ? s * 0.125f : -1e30f;
    }

    if ((l & 3) == 0) {
        float m = -1e30f;
        #pragma unroll
        for (int c = 0; c < 12; ++c) m = fmaxf(m, sco[c]);
        float sum = 0.f;
        #pragma unroll
        for (int c = 0; c < 12; ++c) { float e = __expf(sco[c] - m); sco[c] = e; sum += e; }
        float inv = 1.f / sum;
        #pragma unroll
        for (int c = 0; c < 12; ++c) pr_s[w][h4 * 13 + c] = sco[c] * inv;
    }
    __syncthreads();

    float o[16] = {};
    #pragma unroll
    for (int c = 0; c < 12; ++c) {
        float p = pr_s[w][h4 * 13 + c];
        const bf16x8* vp = (const bf16x8*)(qkv + (size_t)(b * S_ + cols_s[w][c]) * 3072 + 2 * E_);
        bf16x8 v0 = vp[l * 2], v1 = vp[l * 2 + 1];
        #pragma unroll
        for (int j = 0; j < 8; ++j) { o[j] += p * (float)v0[j]; o[8 + j] += p * (float)v1[j]; }
    }

    if (valid) {
        ushort4 u0, u1, u2, u3;
        u0.x = f2bf(o[0]);  u0.y = f2bf(o[1]);  u0.z = f2bf(o[2]);  u0.w = f2bf(o[3]);
        u1.x = f2bf(o[4]);  u1.y = f2bf(o[5]);  u1.z = f2bf(o[6]);  u1.w = f2bf(o[7]);
        u2.x = f2bf(o[8]);  u2.y = f2bf(o[9]);  u2.z = f2bf(o[10]); u2.w = f2bf(o[11]);
        u3.x = f2bf(o[12]); u3.y = f2bf(o[13]); u3.z = f2bf(o[14]); u3.w = f2bf(o[15]);
        ushort4* op = (ushort4*)(attn + (size_t)(b * S_ + i) * E_ + l * 16);
        op[0] = u0; op[1] = u1; op[2] = u2; op[3] = u3;
    }
}

// merge 128 chunk partials per tuple (R7: 64 blocks, 4-way chunk split + LDS combine)
__global__ __launch_bounds__(256)
void gattn_fin(const float* __restrict__ gaccp, const float* __restrict__ gms,
               unsigned short* __restrict__ attn) {
    int tup = blockIdx.x;                       // 64
    int b = tup >> 5, i = (tup >> 4) & 1, h = tup & 15;
    int t = threadIdx.x, g = t >> 6, d = t & 63;
    __shared__ float sM[4], sD[4], sO[4][D_];

    float M = -1e30f;
    #pragma unroll 8
    for (int c = g * 32; c < g * 32 + 32; ++c)
        M = fmaxf(M, gms[((size_t)tup * 128 + c) * 2]);
    float den = 0.f, num = 0.f;
    #pragma unroll 8
    for (int c = g * 32; c < g * 32 + 32; ++c) {
        float f = __expf(gms[((size_t)tup * 128 + c) * 2] - M);
        den += gms[((size_t)tup * 128 + c) * 2 + 1] * f;
        num += gaccp[((size_t)tup * 128 + c) * D_ + d] * f;
    }
    if (d == 0) { sM[g] = M; sD[g] = den; }
    sO[g][d] = num;
    __syncthreads();
    if (g == 0) {
        float MM = fmaxf(fmaxf(sM[0], sM[1]), fmaxf(sM[2], sM[3]));
        float dd = 0.f, nn = 0.f;
        #pragma unroll
        for (int j = 0; j < 4; ++j) {
            float f = __expf(sM[j] - MM);
            dd += sD[j] * f;
            nn += sO[j][d] * f;
        }
        attn[(size_t)(b * S_ + i) * E_ + h * D_ + d] = f2bf(nn / dd);
    }
}

extern "C" void kernel_launch(void* const* d_in, const int* in_sizes, int n_in,
                              void* d_out, int out_size, void* d_ws, size_t ws_size,
                              hipStream_t stream) {
    const float* x   = (const float*)d_in[0];
    const int*   rnd = (const int*)d_in[1];
    const float* qw  = (const float*)d_in[2];
    const float* qb  = (const float*)d_in[3];
    const float* kw  = (const float*)d_in[4];
    const float* kb  = (const float*)d_in[5];
    const float* vw  = (const float*)d_in[6];
    const float* vb  = (const float*)d_in[7];
    const float* ow  = (const float*)d_in[8];
    const float* ob  = (const float*)d_in[9];
    float* out = (float*)d_out;

    char* ws = (char*)d_ws;
    unsigned short* xb    = (unsigned short*)(ws);                       // 8 MB (dead after QKV GEMM)
    unsigned short* wqkv  = (unsigned short*)(ws + 8388608);             // 6 MB
    unsigned short* wo    = (unsigned short*)(ws + 14680064);            // 2 MB
    unsigned short* qkv   = (unsigned short*)(ws + 16777216);            // 24 MB
    unsigned short* attn  = (unsigned short*)(ws + 41943040);            // 8 MB
    float*          gaccp = (float*)(ws);                                // 2 MB (overlaps dead xb)
    float*          gms   = (float*)(ws + 2097152);                      // 64 KB

    const int M = B_ * S_;   // 4096

    {
        int total4 = (M * E_ + 4 * E_ * E_) / 4;
        convert_all<<<total4 / 256, 256, 0, stream>>>(x, qw, kw, vw, ow, xb, wqkv, wo);
    }

    // QKV GEMM: [4096][3072] bf16, BK=64 swizzled, XCD-swizzled 1D grid
    gemm_qkv<<<768, 256, 0, stream>>>(xb, wqkv, qb, kb, vb, qkv, M, 3 * E_, E_);

    // row-streaming global chunks (256) + sparse rows (1024), one dispatch
    attn_fused<<<256 + 1024, 256, 0, stream>>>(qkv, rnd, gaccp, gms, attn);

    // merge global-row partials (128 chunks/tuple, one block per tuple)
    gattn_fin<<<64, 256, 0, stream>>>(gaccp, gms, attn);

    // O GEMM -> fp32 out, 128x128 tile, XCD-swizzled 1D grid
    gemm_o<<<256, 256, 0, stream>>>(attn, wo, ob, out, M, E_, E_);
}